// Round 3
// baseline (312.727 us; speedup 1.0000x reference)
//
#include <hip/hip_runtime.h>
#include <hip/hip_bf16.h>

// Problem constants
#define NN    16      // batch
#define INC   32
#define INN   65536
#define OUTC  32
#define OUTN  8192
#define MAXD  16
#define NC    512     // NN*INC

typedef __attribute__((ext_vector_type(8))) unsigned short ushort8;

// ---------------------------------------------------------------------------
// MEASUREMENT ROUND: kernels are byte-identical to the round-0 best (257.5us)
// config (OTILE=16). kernel_launch enqueues A,A,B,B — both kernels are
// idempotent (A rewrites identical feat, B rewrites identical out), so
// correctness and absmax are unchanged while dur_us gains exactly
// (A_warm + B). This pins down the kernel-vs-harness-overhead split that
// three rounds of modeling could not, and if either kernel exceeds ~84us
// it surfaces in the rocprof top-5 with full counters.
// ---------------------------------------------------------------------------
__global__ __launch_bounds__(256) void transpose_scale_kernel(
    const float* __restrict__ x,
    const float* __restrict__ weight,
    unsigned short* __restrict__ feat)
{
    __shared__ float tile[64][65];       // [j][r], row stride 65 floats
    const int l  = threadIdx.x;          // 0..255
    const int j0 = blockIdx.x * 64;      // 1024 blocks
    const int r0 = blockIdx.y * 64;      // 8 blocks

    #pragma unroll
    for (int it = 0; it < 4; ++it) {
        int idx = it * 256 + l;          // 0..1023
        int rl  = idx >> 4;              // 0..63
        int jj  = idx & 15;              // float4 group along j
        int r   = r0 + rl;
        int c   = r & 31;
        int j   = j0 + jj * 4;
        float4 xv = *reinterpret_cast<const float4*>(x + (size_t)r * INN + j);
        float4 wv = *reinterpret_cast<const float4*>(weight + (size_t)c * INN + j);
        tile[jj * 4 + 0][rl] = xv.x * wv.x;
        tile[jj * 4 + 1][rl] = xv.y * wv.y;
        tile[jj * 4 + 2][rl] = xv.z * wv.z;
        tile[jj * 4 + 3][rl] = xv.w * wv.w;
    }
    __syncthreads();

    #pragma unroll
    for (int p = 0; p < 2; ++p) {
        int jl = p * 32 + (l >> 3);      // 0..63
        int rs = (l & 7) * 8;            // 0..56
        ushort8 pk;
        #pragma unroll
        for (int k = 0; k < 8; ++k) {
            float v = tile[jl][rs + k];
            pk[k] = __bfloat16_as_ushort(__float2bfloat16(v));
        }
        *reinterpret_cast<ushort8*>(
            feat + (size_t)(j0 + jl) * NC + r0 + rs) = pk;
    }
}

#define OTILE 16

__global__ __launch_bounds__(256) void gather_gemm_kernel(
    const unsigned short* __restrict__ feat,
    const int*   __restrict__ A,
    const float* __restrict__ mask,
    const float* __restrict__ mw,
    const float* __restrict__ ctw,
    const float* __restrict__ ctb,
    const float* __restrict__ bias,
    float*       __restrict__ out)
{
    __shared__ float pooled[OTILE][NC];  // 32 KB
    const int l    = threadIdx.x;        // 0..255
    const int wave = l >> 6;             // 0..3
    const int lane = l & 63;
    const int o0   = blockIdx.x * OTILE; // 512 blocks

    // ct_weight row for this thread's dout, into registers (8 x float4).
    const int dout = l & 31;
    float ctr[32];
    #pragma unroll
    for (int q = 0; q < 8; ++q)
        *reinterpret_cast<float4*>(&ctr[4 * q]) =
            *reinterpret_cast<const float4*>(ctw + dout * 32 + 4 * q);
    const float cb = ctb[dout];

    // Gather phase.
    #pragma unroll
    for (int i = 0; i < 4; ++i) {
        const int o  = wave * 4 + i;
        const int oo = o0 + o;
        float acc[8] = {0.f, 0.f, 0.f, 0.f, 0.f, 0.f, 0.f, 0.f};
        #pragma unroll
        for (int d = 0; d < MAXD; ++d) {
            int   j = A[oo * MAXD + d] & (INN - 1);            // wave-uniform
            float w = mw[oo * MAXD + d] * mask[oo * MAXD + d]; // wave-uniform
            ushort8 p = *reinterpret_cast<const ushort8*>(
                feat + (size_t)j * NC + lane * 8);
            #pragma unroll
            for (int k = 0; k < 8; ++k)
                acc[k] += w * __uint_as_float((unsigned)p[k] << 16);
        }
        *reinterpret_cast<float4*>(&pooled[o][lane * 8]) =
            make_float4(acc[0], acc[1], acc[2], acc[3]);
        *reinterpret_cast<float4*>(&pooled[o][lane * 8 + 4]) =
            make_float4(acc[4], acc[5], acc[6], acc[7]);
    }
    __syncthreads();

    // GEMM phase: 512 (n,dout) pairs, 2 n's per thread.
    #pragma unroll
    for (int h = 0; h < 2; ++h) {
        const int n = (l >> 5) + 8 * h;  // 0..15
        float vals[OTILE];
        #pragma unroll
        for (int o = 0; o < OTILE; ++o) {
            float s = cb;
            #pragma unroll
            for (int q = 0; q < 8; ++q) {
                float4 pv = *reinterpret_cast<const float4*>(
                    &pooled[o][n * 32 + 4 * q]);        // broadcast read
                s += pv.x * ctr[4 * q + 0] + pv.y * ctr[4 * q + 1]
                   + pv.z * ctr[4 * q + 2] + pv.w * ctr[4 * q + 3];
            }
            vals[o] = s + bias[(size_t)dout * OUTN + o0 + o];
        }
        float4* outp = reinterpret_cast<float4*>(
            out + ((size_t)(n * 32 + dout)) * OUTN + o0);
        #pragma unroll
        for (int q = 0; q < 4; ++q)
            outp[q] = make_float4(vals[4*q], vals[4*q+1], vals[4*q+2], vals[4*q+3]);
    }
}

extern "C" void kernel_launch(void* const* d_in, const int* in_sizes, int n_in,
                              void* d_out, int out_size, void* d_ws, size_t ws_size,
                              hipStream_t stream)
{
    const float* x      = (const float*)d_in[0];   // (16,32,65536)
    const int*   A      = (const int*)  d_in[1];   // (8192,16)
    const float* weight = (const float*)d_in[2];   // (32,65536)
    const float* mask   = (const float*)d_in[3];   // (8192,16,1)
    const float* mw     = (const float*)d_in[4];   // (8192,16,1)
    const float* ctw    = (const float*)d_in[5];   // (32,32)
    const float* ctb    = (const float*)d_in[6];   // (32,)
    const float* bias   = (const float*)d_in[7];   // (32,8192)
    float* out = (float*)d_out;                    // (16,32,8192)

    unsigned short* feat = (unsigned short*)d_ws;  // (65536, 512) bf16 = 67 MB

    dim3 gA(INN / 64, NC / 64);                    // 1024 x 8

    // Duplicated launches (idempotent): dur delta vs round-0 = A_warm + B.
    transpose_scale_kernel<<<gA, 256, 0, stream>>>(x, weight, feat);
    transpose_scale_kernel<<<gA, 256, 0, stream>>>(x, weight, feat);

    gather_gemm_kernel<<<OUTN / OTILE, 256, 0, stream>>>(
        feat, A, mask, mw, ctw, ctb, bias, out);
    gather_gemm_kernel<<<OUTN / OTILE, 256, 0, stream>>>(
        feat, A, mask, mw, ctw, ctb, bias, out);
}

// Round 5
// 263.007 us; speedup vs baseline: 1.1890x; 1.1890x over previous
//
#include <hip/hip_runtime.h>
#include <hip/hip_bf16.h>

// Problem constants
#define NN    16      // batch
#define INC   32
#define INN   65536
#define OUTC  32
#define OUTN  8192
#define MAXD  16
#define NC    512     // NN*INC

typedef __attribute__((ext_vector_type(8))) unsigned short ushort8;
typedef __attribute__((ext_vector_type(4))) float float4v;  // native vector:
// __builtin_nontemporal_* requires scalar/clang-vector types, not
// HIP_vector_type<float,4> (round-4 compile failure).

// ---------------------------------------------------------------------------
// Kernel A: feat[j][r] = x[r][j] * weight[r&31][j], stored bf16 (as ushort).
// Round-0 structure (best measured: 257.5us total). x loads are marked
// non-temporal: x is read exactly once globally, and evict-first keeps the
// 67 MB feat write resident in Infinity Cache for kernel B's random gather.
// weight (8 MB, re-read across blockIdx.y) stays cached normally.
// Session accounting (round-3 A,A,B,B probe): A_cold+B ~= 57-62us of the
// 257.5us; the rest is harness-fixed poison fills (~2 x 85us) + gaps.
// ---------------------------------------------------------------------------
__global__ __launch_bounds__(256) void transpose_scale_kernel(
    const float* __restrict__ x,
    const float* __restrict__ weight,
    unsigned short* __restrict__ feat)
{
    __shared__ float tile[64][65];       // [j][r], row stride 65 floats
    const int l  = threadIdx.x;          // 0..255
    const int j0 = blockIdx.x * 64;      // 1024 blocks
    const int r0 = blockIdx.y * 64;      // 8 blocks

    #pragma unroll
    for (int it = 0; it < 4; ++it) {
        int idx = it * 256 + l;          // 0..1023
        int rl  = idx >> 4;              // 0..63
        int jj  = idx & 15;              // float4 group along j
        int r   = r0 + rl;
        int c   = r & 31;
        int j   = j0 + jj * 4;
        float4v xv = __builtin_nontemporal_load(
            reinterpret_cast<const float4v*>(x + (size_t)r * INN + j));
        float4 wv = *reinterpret_cast<const float4*>(weight + (size_t)c * INN + j);
        tile[jj * 4 + 0][rl] = xv.x * wv.x;
        tile[jj * 4 + 1][rl] = xv.y * wv.y;
        tile[jj * 4 + 2][rl] = xv.z * wv.z;
        tile[jj * 4 + 3][rl] = xv.w * wv.w;
    }
    __syncthreads();

    #pragma unroll
    for (int p = 0; p < 2; ++p) {
        int jl = p * 32 + (l >> 3);      // 0..63
        int rs = (l & 7) * 8;            // 0..56
        ushort8 pk;
        #pragma unroll
        for (int k = 0; k < 8; ++k) {
            float v = tile[jl][rs + k];
            pk[k] = __bfloat16_as_ushort(__float2bfloat16(v));
        }
        *reinterpret_cast<ushort8*>(
            feat + (size_t)(j0 + jl) * NC + r0 + rs) = pk;
    }
}

// ---------------------------------------------------------------------------
// Kernel B: round-0 structure (OTILE=16, 4 o/wave — best of the three
// measured configs: beats OTILE=8/more-blocks and 2-dout register blocking,
// both of which regressed). out stores are non-temporal (never re-read;
// avoids evicting feat from L3 while other blocks still gather).
// ---------------------------------------------------------------------------
#define OTILE 16

__global__ __launch_bounds__(256) void gather_gemm_kernel(
    const unsigned short* __restrict__ feat,
    const int*   __restrict__ A,
    const float* __restrict__ mask,
    const float* __restrict__ mw,
    const float* __restrict__ ctw,
    const float* __restrict__ ctb,
    const float* __restrict__ bias,
    float*       __restrict__ out)
{
    __shared__ float pooled[OTILE][NC];  // 32 KB
    const int l    = threadIdx.x;        // 0..255
    const int wave = l >> 6;             // 0..3
    const int lane = l & 63;
    const int o0   = blockIdx.x * OTILE; // 512 blocks

    // ct_weight row for this thread's dout, into registers (8 x float4).
    const int dout = l & 31;
    float ctr[32];
    #pragma unroll
    for (int q = 0; q < 8; ++q)
        *reinterpret_cast<float4*>(&ctr[4 * q]) =
            *reinterpret_cast<const float4*>(ctw + dout * 32 + 4 * q);
    const float cb = ctb[dout];

    // Gather phase.
    #pragma unroll
    for (int i = 0; i < 4; ++i) {
        const int o  = wave * 4 + i;
        const int oo = o0 + o;
        float acc[8] = {0.f, 0.f, 0.f, 0.f, 0.f, 0.f, 0.f, 0.f};
        #pragma unroll
        for (int d = 0; d < MAXD; ++d) {
            int   j = A[oo * MAXD + d] & (INN - 1);            // wave-uniform
            float w = mw[oo * MAXD + d] * mask[oo * MAXD + d]; // wave-uniform
            ushort8 p = *reinterpret_cast<const ushort8*>(
                feat + (size_t)j * NC + lane * 8);
            #pragma unroll
            for (int k = 0; k < 8; ++k)
                acc[k] += w * __uint_as_float((unsigned)p[k] << 16);
        }
        *reinterpret_cast<float4*>(&pooled[o][lane * 8]) =
            make_float4(acc[0], acc[1], acc[2], acc[3]);
        *reinterpret_cast<float4*>(&pooled[o][lane * 8 + 4]) =
            make_float4(acc[4], acc[5], acc[6], acc[7]);
    }
    __syncthreads();

    // GEMM phase: 512 (n,dout) pairs, 2 n's per thread.
    #pragma unroll
    for (int h = 0; h < 2; ++h) {
        const int n = (l >> 5) + 8 * h;  // 0..15
        float vals[OTILE];
        #pragma unroll
        for (int o = 0; o < OTILE; ++o) {
            float s = cb;
            #pragma unroll
            for (int q = 0; q < 8; ++q) {
                float4 pv = *reinterpret_cast<const float4*>(
                    &pooled[o][n * 32 + 4 * q]);        // broadcast read
                s += pv.x * ctr[4 * q + 0] + pv.y * ctr[4 * q + 1]
                   + pv.z * ctr[4 * q + 2] + pv.w * ctr[4 * q + 3];
            }
            vals[o] = s + bias[(size_t)dout * OUTN + o0 + o];
        }
        float4v* outp = reinterpret_cast<float4v*>(
            out + ((size_t)(n * 32 + dout)) * OUTN + o0);
        #pragma unroll
        for (int q = 0; q < 4; ++q) {
            float4v ov = {vals[4*q], vals[4*q+1], vals[4*q+2], vals[4*q+3]};
            __builtin_nontemporal_store(ov, outp + q);
        }
    }
}

extern "C" void kernel_launch(void* const* d_in, const int* in_sizes, int n_in,
                              void* d_out, int out_size, void* d_ws, size_t ws_size,
                              hipStream_t stream)
{
    const float* x      = (const float*)d_in[0];   // (16,32,65536)
    const int*   A      = (const int*)  d_in[1];   // (8192,16)
    const float* weight = (const float*)d_in[2];   // (32,65536)
    const float* mask   = (const float*)d_in[3];   // (8192,16,1)
    const float* mw     = (const float*)d_in[4];   // (8192,16,1)
    const float* ctw    = (const float*)d_in[5];   // (32,32)
    const float* ctb    = (const float*)d_in[6];   // (32,)
    const float* bias   = (const float*)d_in[7];   // (32,8192)
    float* out = (float*)d_out;                    // (16,32,8192)

    unsigned short* feat = (unsigned short*)d_ws;  // (65536, 512) bf16 = 67 MB

    dim3 gA(INN / 64, NC / 64);                    // 1024 x 8
    transpose_scale_kernel<<<gA, 256, 0, stream>>>(x, weight, feat);

    gather_gemm_kernel<<<OUTN / OTILE, 256, 0, stream>>>(
        feat, A, mask, mw, ctw, ctb, bias, out);
}

// Round 6
// 259.025 us; speedup vs baseline: 1.2073x; 1.0154x over previous
//
#include <hip/hip_runtime.h>
#include <hip/hip_bf16.h>

// Problem constants
#define NN    16      // batch
#define INC   32
#define INN   65536
#define OUTC  32
#define OUTN  8192
#define MAXD  16
#define NC    512     // NN*INC

typedef __attribute__((ext_vector_type(8))) unsigned short ushort8;

// ---------------------------------------------------------------------------
// FINAL (reverted to round-0 best, 257.5us measured).
// Session accounting (round-3 idempotent-duplication probe, A,A,B,B):
//   A_warm + B = 55.2us directly measured  ->  A_cold + B ~= 57-62us.
//   Remaining ~195-200us of dur_us is harness-fixed: two 512 MiB
//   workspace-poison fills at 6.3-6.9 TB/s (HBM-write roofline) + gaps.
// Kernel share sits within ~10% of its memory floor (~51-58us):
//   A: 209 MB HBM (x 134 + weight 8 + feat 67) ~= 33us
//   B: 134 MB L3-resident gather + 16 MB out   ~= 18-25us
// Probed and rejected: OTILE=8 / 2x blocks (+4us), 2-dout register
// blocking (+12us, occupancy cliff), NT evict-first hints (+5us null).
// ---------------------------------------------------------------------------
__global__ __launch_bounds__(256) void transpose_scale_kernel(
    const float* __restrict__ x,
    const float* __restrict__ weight,
    unsigned short* __restrict__ feat)
{
    __shared__ float tile[64][65];       // [j][r], row stride 65 floats
    const int l  = threadIdx.x;          // 0..255
    const int j0 = blockIdx.x * 64;      // 1024 blocks
    const int r0 = blockIdx.y * 64;      // 8 blocks

    #pragma unroll
    for (int it = 0; it < 4; ++it) {
        int idx = it * 256 + l;          // 0..1023
        int rl  = idx >> 4;              // 0..63
        int jj  = idx & 15;              // float4 group along j
        int r   = r0 + rl;
        int c   = r & 31;
        int j   = j0 + jj * 4;
        float4 xv = *reinterpret_cast<const float4*>(x + (size_t)r * INN + j);
        float4 wv = *reinterpret_cast<const float4*>(weight + (size_t)c * INN + j);
        tile[jj * 4 + 0][rl] = xv.x * wv.x;
        tile[jj * 4 + 1][rl] = xv.y * wv.y;
        tile[jj * 4 + 2][rl] = xv.z * wv.z;
        tile[jj * 4 + 3][rl] = xv.w * wv.w;
    }
    __syncthreads();

    #pragma unroll
    for (int p = 0; p < 2; ++p) {
        int jl = p * 32 + (l >> 3);      // 0..63
        int rs = (l & 7) * 8;            // 0..56
        ushort8 pk;
        #pragma unroll
        for (int k = 0; k < 8; ++k) {
            float v = tile[jl][rs + k];
            pk[k] = __bfloat16_as_ushort(__float2bfloat16(v));
        }
        *reinterpret_cast<ushort8*>(
            feat + (size_t)(j0 + jl) * NC + r0 + rs) = pk;
    }
}

#define OTILE 16

__global__ __launch_bounds__(256) void gather_gemm_kernel(
    const unsigned short* __restrict__ feat,
    const int*   __restrict__ A,
    const float* __restrict__ mask,
    const float* __restrict__ mw,
    const float* __restrict__ ctw,
    const float* __restrict__ ctb,
    const float* __restrict__ bias,
    float*       __restrict__ out)
{
    __shared__ float pooled[OTILE][NC];  // 32 KB
    const int l    = threadIdx.x;        // 0..255
    const int wave = l >> 6;             // 0..3
    const int lane = l & 63;
    const int o0   = blockIdx.x * OTILE; // 512 blocks

    // ct_weight row for this thread's dout, into registers (8 x float4).
    const int dout = l & 31;
    float ctr[32];
    #pragma unroll
    for (int q = 0; q < 8; ++q)
        *reinterpret_cast<float4*>(&ctr[4 * q]) =
            *reinterpret_cast<const float4*>(ctw + dout * 32 + 4 * q);
    const float cb = ctb[dout];

    // Gather phase: wave w handles o = 4w+i; 64 lanes x 16B = one full 1KB
    // feat row per load instruction; 16 independent loads in flight per o.
    #pragma unroll
    for (int i = 0; i < 4; ++i) {
        const int o  = wave * 4 + i;
        const int oo = o0 + o;
        float acc[8] = {0.f, 0.f, 0.f, 0.f, 0.f, 0.f, 0.f, 0.f};
        #pragma unroll
        for (int d = 0; d < MAXD; ++d) {
            int   j = A[oo * MAXD + d] & (INN - 1);            // wave-uniform
            float w = mw[oo * MAXD + d] * mask[oo * MAXD + d]; // wave-uniform
            ushort8 p = *reinterpret_cast<const ushort8*>(
                feat + (size_t)j * NC + lane * 8);
            #pragma unroll
            for (int k = 0; k < 8; ++k)
                acc[k] += w * __uint_as_float((unsigned)p[k] << 16);
        }
        *reinterpret_cast<float4*>(&pooled[o][lane * 8]) =
            make_float4(acc[0], acc[1], acc[2], acc[3]);
        *reinterpret_cast<float4*>(&pooled[o][lane * 8 + 4]) =
            make_float4(acc[4], acc[5], acc[6], acc[7]);
    }
    __syncthreads();

    // GEMM phase: 512 (n,dout) pairs, 2 n's per thread.
    #pragma unroll
    for (int h = 0; h < 2; ++h) {
        const int n = (l >> 5) + 8 * h;  // 0..15
        float vals[OTILE];
        #pragma unroll
        for (int o = 0; o < OTILE; ++o) {
            float s = cb;
            #pragma unroll
            for (int q = 0; q < 8; ++q) {
                float4 pv = *reinterpret_cast<const float4*>(
                    &pooled[o][n * 32 + 4 * q]);        // broadcast read
                s += pv.x * ctr[4 * q + 0] + pv.y * ctr[4 * q + 1]
                   + pv.z * ctr[4 * q + 2] + pv.w * ctr[4 * q + 3];
            }
            vals[o] = s + bias[(size_t)dout * OUTN + o0 + o];
        }
        float4* outp = reinterpret_cast<float4*>(
            out + ((size_t)(n * 32 + dout)) * OUTN + o0);
        #pragma unroll
        for (int q = 0; q < 4; ++q)
            outp[q] = make_float4(vals[4*q], vals[4*q+1], vals[4*q+2], vals[4*q+3]);
    }
}

extern "C" void kernel_launch(void* const* d_in, const int* in_sizes, int n_in,
                              void* d_out, int out_size, void* d_ws, size_t ws_size,
                              hipStream_t stream)
{
    const float* x      = (const float*)d_in[0];   // (16,32,65536)
    const int*   A      = (const int*)  d_in[1];   // (8192,16)
    const float* weight = (const float*)d_in[2];   // (32,65536)
    const float* mask   = (const float*)d_in[3];   // (8192,16,1)
    const float* mw     = (const float*)d_in[4];   // (8192,16,1)
    const float* ctw    = (const float*)d_in[5];   // (32,32)
    const float* ctb    = (const float*)d_in[6];   // (32,)
    const float* bias   = (const float*)d_in[7];   // (32,8192)
    float* out = (float*)d_out;                    // (16,32,8192)

    unsigned short* feat = (unsigned short*)d_ws;  // (65536, 512) bf16 = 67 MB

    dim3 gA(INN / 64, NC / 64);                    // 1024 x 8
    transpose_scale_kernel<<<gA, 256, 0, stream>>>(x, weight, feat);

    gather_gemm_kernel<<<OUTN / OTILE, 256, 0, stream>>>(
        feat, A, mask, mw, ctw, ctb, bias, out);
}